// Round 1
// baseline (159.234 us; speedup 1.0000x reference)
//
#include <hip/hip_runtime.h>
#include <hip/hip_bf16.h>

#define B_ 4
#define T_ 4096
#define C_ 1024
#define H_ 64

typedef __bf16 bf16_t;
typedef __bf16 bf16x8 __attribute__((ext_vector_type(8)));
typedef float f32x4 __attribute__((ext_vector_type(4)));

// ---------------- Kernel A: convert W (3 x [64][1024] fp32) -> bf16 ----------------
__global__ void wcvt_kernel(const float* __restrict__ Wq, const float* __restrict__ Wk,
                            const float* __restrict__ Wv, bf16_t* __restrict__ wbf) {
    int i = blockIdx.x * 256 + threadIdx.x;          // 0 .. 196607
    int m = i >> 16;
    int r = i & 65535;
    const float* src = (m == 0) ? Wq : (m == 1) ? Wk : Wv;
    wbf[i] = (bf16_t)src[r];
}

// ---------------- Kernel B: QKV projection ----------------
// y = x @ W^T for 3 weight matrices. M = B*T = 16384, K = 1024, N = 64 each.
// Grid 256 blocks x 256 threads (4 waves). Each wave: 16 rows, all 192 output cols.
// Writes q,k row-major [B*T][64] bf16; v transposed [B][64][T] bf16.
__global__ __launch_bounds__(256)
void qkv_proj_kernel(const float* __restrict__ x, const bf16_t* __restrict__ wbf,
                     bf16_t* __restrict__ qb, bf16_t* __restrict__ kb,
                     bf16_t* __restrict__ vtb) {
    int tid  = threadIdx.x;
    int w    = tid >> 6;
    int lane = tid & 63;
    int lr   = lane & 15;      // A-frag row / B-frag col
    int kg   = lane >> 4;      // k-group (0..3), k offset = kg*8

    int row = blockIdx.x * 64 + w * 16 + lr;
    const float* xr = x + (size_t)row * C_ + kg * 8;

    f32x4 acc[3][4];
    #pragma unroll
    for (int m = 0; m < 3; ++m)
        #pragma unroll
        for (int ct = 0; ct < 4; ++ct)
            acc[m][ct] = (f32x4){0.f, 0.f, 0.f, 0.f};

    #pragma unroll 2
    for (int k0 = 0; k0 < C_; k0 += 32) {
        float4 a0 = *(const float4*)(xr + k0);
        float4 a1 = *(const float4*)(xr + k0 + 4);
        bf16x8 af;
        af[0] = (bf16_t)a0.x; af[1] = (bf16_t)a0.y; af[2] = (bf16_t)a0.z; af[3] = (bf16_t)a0.w;
        af[4] = (bf16_t)a1.x; af[5] = (bf16_t)a1.y; af[6] = (bf16_t)a1.z; af[7] = (bf16_t)a1.w;
        #pragma unroll
        for (int m = 0; m < 3; ++m) {
            #pragma unroll
            for (int ct = 0; ct < 4; ++ct) {
                bf16x8 bf = *(const bf16x8*)&wbf[(size_t)m * 65536 +
                                                 (size_t)(ct * 16 + lr) * 1024 + k0 + kg * 8];
                acc[m][ct] = __builtin_amdgcn_mfma_f32_16x16x32_bf16(af, bf, acc[m][ct], 0, 0, 0);
            }
        }
    }

    // C/D layout: col = lane&15 (-> h), row = (lane>>4)*4 + i (-> t within 16-row tile)
    int rowst = blockIdx.x * 64 + w * 16 + kg * 4;
    #pragma unroll
    for (int ct = 0; ct < 4; ++ct) {
        int h = ct * 16 + lr;
        #pragma unroll
        for (int i = 0; i < 4; ++i) {
            int t = rowst + i;
            qb[(size_t)t * 64 + h] = (bf16_t)acc[0][ct][i];
            kb[(size_t)t * 64 + h] = (bf16_t)acc[1][ct][i];
            int b  = t >> 12;
            int tt = t & 4095;
            vtb[((size_t)b * 64 + h) * T_ + tt] = (bf16_t)acc[2][ct][i];
        }
    }
}

// ---------------- Kernel C: causal flash attention ----------------
// grid = 512 blocks (B=4 x 128 q-tiles of 32 rows), 128 threads (2 waves, 16 rows each).
// KV tiles of 64 staged in LDS. Online softmax in fp32; QK^T and PV via bf16 MFMA.
__global__ __launch_bounds__(128)
void attn_kernel(const bf16_t* __restrict__ qb, const bf16_t* __restrict__ kb,
                 const bf16_t* __restrict__ vtb, float* __restrict__ out) {
    __shared__ bf16_t k_lds[64][72];      // [kv][c]  (pitch 72 kills 128B-stride conflicts)
    __shared__ bf16_t v_lds[64][72];      // [h][kv]  (v stored transposed in ws)
    __shared__ bf16_t p_lds[2][16][72];   // per-wave P buffer [qrow][kv]

    int tid  = threadIdx.x;
    int bid  = blockIdx.x;
    int b    = bid & 3;
    int qt   = 127 - (bid >> 2);          // diagonal-heavy tiles first
    int w    = tid >> 6;
    int lane = tid & 63;
    int lr   = lane & 15;
    int kg   = lane >> 4;

    int qrow0 = qt * 32 + w * 16;         // wave's first q row

    // Q fragments (held in registers for the whole kernel)
    bf16x8 qf[2];
    #pragma unroll
    for (int s = 0; s < 2; ++s)
        qf[s] = *(const bf16x8*)&qb[((size_t)(b * T_ + qrow0 + lr)) * 64 + s * 32 + kg * 8];

    f32x4 o_acc[4];
    float m_i[4], l_i[4];
    #pragma unroll
    for (int ct = 0; ct < 4; ++ct) o_acc[ct] = (f32x4){0.f, 0.f, 0.f, 0.f};
    #pragma unroll
    for (int i = 0; i < 4; ++i) { m_i[i] = -INFINITY; l_i[i] = 0.f; }

    int n_iter = (qt >> 1) + 1;
    for (int it = 0; it < n_iter; ++it) {
        int kv0 = it * 64;
        __syncthreads();
        // stage K tile [64][64] and V^T tile [64][64] (coalesced 16B segments)
        #pragma unroll
        for (int s = 0; s < 4; ++s) {
            int linear = tid + s * 128;         // 0..511
            int r  = linear >> 3;
            int c8 = (linear & 7) * 8;
            *(bf16x8*)&k_lds[r][c8] = *(const bf16x8*)&kb[((size_t)(b * T_ + kv0 + r)) * 64 + c8];
            *(bf16x8*)&v_lds[r][c8] = *(const bf16x8*)&vtb[((size_t)(b * 64 + r)) * T_ + kv0 + c8];
        }
        __syncthreads();

        // S = Q K^T  (4 col-tiles of 16, 2 k-steps over D=64)
        f32x4 sc[4];
        #pragma unroll
        for (int ct = 0; ct < 4; ++ct) {
            sc[ct] = (f32x4){0.f, 0.f, 0.f, 0.f};
            #pragma unroll
            for (int s = 0; s < 2; ++s) {
                bf16x8 kf = *(const bf16x8*)&k_lds[ct * 16 + lr][s * 32 + kg * 8];
                sc[ct] = __builtin_amdgcn_mfma_f32_16x16x32_bf16(qf[s], kf, sc[ct], 0, 0, 0);
            }
        }

        bool lastTile = (it == n_iter - 1);
        float sv[4][4];
        #pragma unroll
        for (int ct = 0; ct < 4; ++ct)
            #pragma unroll
            for (int i = 0; i < 4; ++i) {
                float v = sc[ct][i] * 0.125f;
                if (lastTile) {
                    int col = kv0 + ct * 16 + lr;
                    int rw  = qrow0 + kg * 4 + i;
                    if (col > rw) v = -INFINITY;
                }
                sv[ct][i] = v;
            }

        // row max over 64 cols: local over ct, then shuffle over 16-lane row group
        float rmax[4];
        #pragma unroll
        for (int i = 0; i < 4; ++i)
            rmax[i] = fmaxf(fmaxf(sv[0][i], sv[1][i]), fmaxf(sv[2][i], sv[3][i]));
        #pragma unroll
        for (int off = 1; off < 16; off <<= 1)
            #pragma unroll
            for (int i = 0; i < 4; ++i)
                rmax[i] = fmaxf(rmax[i], __shfl_xor(rmax[i], off));

        float fs[4];
        #pragma unroll
        for (int i = 0; i < 4; ++i) {
            float mn = fmaxf(m_i[i], rmax[i]);
            fs[i] = __expf(m_i[i] - mn);
            m_i[i] = mn;
        }

        float rsum[4] = {0.f, 0.f, 0.f, 0.f};
        #pragma unroll
        for (int ct = 0; ct < 4; ++ct)
            #pragma unroll
            for (int i = 0; i < 4; ++i) {
                float p = __expf(sv[ct][i] - m_i[i]);
                p_lds[w][kg * 4 + i][ct * 16 + lr] = (bf16_t)p;
                rsum[i] += p;
            }
        #pragma unroll
        for (int off = 1; off < 16; off <<= 1)
            #pragma unroll
            for (int i = 0; i < 4; ++i)
                rsum[i] += __shfl_xor(rsum[i], off);

        #pragma unroll
        for (int i = 0; i < 4; ++i)
            l_i[i] = l_i[i] * fs[i] + rsum[i];
        #pragma unroll
        for (int ct = 0; ct < 4; ++ct)
            #pragma unroll
            for (int i = 0; i < 4; ++i)
                o_acc[ct][i] *= fs[i];

        // O += P V   (A-frag = P from per-wave LDS, B-frag = V^T rows)
        bf16x8 pf[2];
        #pragma unroll
        for (int s = 0; s < 2; ++s)
            pf[s] = *(const bf16x8*)&p_lds[w][lr][s * 32 + kg * 8];
        #pragma unroll
        for (int ct = 0; ct < 4; ++ct)
            #pragma unroll
            for (int s = 0; s < 2; ++s) {
                bf16x8 vf = *(const bf16x8*)&v_lds[ct * 16 + lr][s * 32 + kg * 8];
                o_acc[ct] = __builtin_amdgcn_mfma_f32_16x16x32_bf16(pf[s], vf, o_acc[ct], 0, 0, 0);
            }
    }

    // epilogue: O / l
    #pragma unroll
    for (int ct = 0; ct < 4; ++ct)
        #pragma unroll
        for (int i = 0; i < 4; ++i) {
            int rw = qrow0 + kg * 4 + i;
            out[((size_t)(b * T_ + rw)) * 64 + ct * 16 + lr] = o_acc[ct][i] / l_i[i];
        }
}

extern "C" void kernel_launch(void* const* d_in, const int* in_sizes, int n_in,
                              void* d_out, int out_size, void* d_ws, size_t ws_size,
                              hipStream_t stream) {
    const float* x  = (const float*)d_in[0];
    const float* Wq = (const float*)d_in[1];
    const float* Wk = (const float*)d_in[2];
    const float* Wv = (const float*)d_in[3];
    float* out = (float*)d_out;

    bf16_t* ws  = (bf16_t*)d_ws;
    bf16_t* wbf = ws;                    // 3*64*1024       = 196608 elems
    bf16_t* qb  = ws + 196608;           // 16384*64        = 1048576
    bf16_t* kb  = qb + 1048576;
    bf16_t* vtb = kb + 1048576;          // [B][64][T]

    wcvt_kernel<<<768, 256, 0, stream>>>(Wq, Wk, Wv, wbf);
    qkv_proj_kernel<<<256, 256, 0, stream>>>(x, wbf, qb, kb, vtb);
    attn_kernel<<<512, 128, 0, stream>>>(qb, kb, vtb, out);
}

// Round 2
// 155.871 us; speedup vs baseline: 1.0216x; 1.0216x over previous
//
#include <hip/hip_runtime.h>
#include <hip/hip_bf16.h>

#define B_ 4
#define T_ 4096
#define C_ 1024
#define H_ 64

typedef __bf16 bf16_t;
typedef __bf16 bf16x8 __attribute__((ext_vector_type(8)));
typedef float f32x4 __attribute__((ext_vector_type(4)));

// ---------------- Kernel A: convert W (3 x [64][1024] fp32) -> bf16 ----------------
__global__ void wcvt_kernel(const float* __restrict__ Wq, const float* __restrict__ Wk,
                            const float* __restrict__ Wv, bf16_t* __restrict__ wbf) {
    int i = blockIdx.x * 256 + threadIdx.x;          // 0 .. 196607
    int m = i >> 16;
    int r = i & 65535;
    const float* src = (m == 0) ? Wq : (m == 1) ? Wk : Wv;
    wbf[i] = (bf16_t)src[r];
}

// ---------------- Kernel B: QKV projection (matrix-split for occupancy) ----------------
// grid = 768 blocks (3 matrices x 256 row-tiles), 256 threads (4 waves x 16 rows).
// x re-read 3x but L3-resident (64 MB < 256 MB). Q written pre-scaled by 1/8.
__global__ __launch_bounds__(256)
void qkv_proj_kernel(const float* __restrict__ x, const bf16_t* __restrict__ wbf,
                     bf16_t* __restrict__ qb, bf16_t* __restrict__ kb,
                     bf16_t* __restrict__ vtb) {
    int tid  = threadIdx.x;
    int w    = tid >> 6;
    int lane = tid & 63;
    int lr   = lane & 15;      // A-frag row / B-frag col
    int kg   = lane >> 4;      // k-group (0..3), k offset = kg*8

    int m      = blockIdx.x >> 8;     // 0=q, 1=k, 2=v
    int rowblk = blockIdx.x & 255;

    int row = rowblk * 64 + w * 16 + lr;
    const float* xr = x + (size_t)row * C_ + kg * 8;
    const bf16_t* wm = wbf + (size_t)m * 65536;

    f32x4 acc[4];
    #pragma unroll
    for (int ct = 0; ct < 4; ++ct) acc[ct] = (f32x4){0.f, 0.f, 0.f, 0.f};

    #pragma unroll 4
    for (int k0 = 0; k0 < C_; k0 += 32) {
        float4 a0 = *(const float4*)(xr + k0);
        float4 a1 = *(const float4*)(xr + k0 + 4);
        bf16x8 af;
        af[0] = (bf16_t)a0.x; af[1] = (bf16_t)a0.y; af[2] = (bf16_t)a0.z; af[3] = (bf16_t)a0.w;
        af[4] = (bf16_t)a1.x; af[5] = (bf16_t)a1.y; af[6] = (bf16_t)a1.z; af[7] = (bf16_t)a1.w;
        #pragma unroll
        for (int ct = 0; ct < 4; ++ct) {
            bf16x8 bf = *(const bf16x8*)&wm[(size_t)(ct * 16 + lr) * 1024 + k0 + kg * 8];
            acc[ct] = __builtin_amdgcn_mfma_f32_16x16x32_bf16(af, bf, acc[ct], 0, 0, 0);
        }
    }

    // C/D layout: col = lane&15 (-> h), row = (lane>>4)*4 + i
    int rowst = rowblk * 64 + w * 16 + kg * 4;
    #pragma unroll
    for (int ct = 0; ct < 4; ++ct) {
        int h = ct * 16 + lr;
        #pragma unroll
        for (int i = 0; i < 4; ++i) {
            int t = rowst + i;
            if (m == 0) {
                qb[(size_t)t * 64 + h] = (bf16_t)(acc[ct][i] * 0.125f);  // pre-scale
            } else if (m == 1) {
                kb[(size_t)t * 64 + h] = (bf16_t)acc[ct][i];
            } else {
                int b  = t >> 12;
                int tt = t & 4095;
                vtb[((size_t)b * 64 + h) * T_ + tt] = (bf16_t)acc[ct][i];
            }
        }
    }
}

// ---------------- Kernel C: causal flash attention ----------------
// grid = 1024 blocks (one per 16-row q-tile, diag-heavy first), 256 threads.
// 4 independent waves split the KV range (strided 64-chunks); no barriers in the
// main loop; K/V read directly from global (L2/L3-resident). End-of-block LDS combine.
__global__ __launch_bounds__(256)
void attn_kernel(const bf16_t* __restrict__ qb, const bf16_t* __restrict__ kb,
                 const bf16_t* __restrict__ vtb, float* __restrict__ out) {
    __shared__ float  olds[4][16][65];
    __shared__ float  mlds[4][16];
    __shared__ float  llds[4][16];
    __shared__ bf16_t p_lds[4][16][66];

    int tid  = threadIdx.x;
    int w    = tid >> 6;
    int lane = tid & 63;
    int lr   = lane & 15;
    int kg   = lane >> 4;

    int bid  = blockIdx.x;
    int b    = bid & 3;
    int t    = 255 - (bid >> 2);      // long tiles dispatched first
    int qrow0 = t * 16;

    // Q fragments (pre-scaled by 1/8)
    bf16x8 qf[2];
    #pragma unroll
    for (int s = 0; s < 2; ++s)
        qf[s] = *(const bf16x8*)&qb[((size_t)(b * T_ + qrow0 + lr)) * 64 + s * 32 + kg * 8];

    f32x4 o_acc[4];
    float m_i[4], l_i[4];
    #pragma unroll
    for (int ct = 0; ct < 4; ++ct) o_acc[ct] = (f32x4){0.f, 0.f, 0.f, 0.f};
    #pragma unroll
    for (int i = 0; i < 4; ++i) { m_i[i] = -INFINITY; l_i[i] = 0.f; }

    int nchunks = (t >> 2) + 1;       // ceil((t*16+16)/64)
    for (int c = w; c < nchunks; c += 4) {
        int kv0 = c * 64;

        // S = Q K^T, K frags straight from global (L2-hit)
        f32x4 sc[4];
        #pragma unroll
        for (int ct = 0; ct < 4; ++ct) sc[ct] = (f32x4){0.f, 0.f, 0.f, 0.f};
        __builtin_amdgcn_s_setprio(1);
        #pragma unroll
        for (int ct = 0; ct < 4; ++ct) {
            #pragma unroll
            for (int s = 0; s < 2; ++s) {
                bf16x8 kf = *(const bf16x8*)&kb[((size_t)(b * T_ + kv0 + ct * 16 + lr)) * 64 + s * 32 + kg * 8];
                sc[ct] = __builtin_amdgcn_mfma_f32_16x16x32_bf16(qf[s], kf, sc[ct], 0, 0, 0);
            }
        }
        __builtin_amdgcn_s_setprio(0);

        bool needMask = (kv0 + 63 > qrow0);
        float sv[4][4];
        #pragma unroll
        for (int ct = 0; ct < 4; ++ct)
            #pragma unroll
            for (int i = 0; i < 4; ++i) {
                float v = sc[ct][i];
                if (needMask) {
                    int col = kv0 + ct * 16 + lr;
                    int rw  = qrow0 + kg * 4 + i;
                    if (col > rw) v = -INFINITY;
                }
                sv[ct][i] = v;
            }

        // row max over 64 cols
        float rmax[4];
        #pragma unroll
        for (int i = 0; i < 4; ++i)
            rmax[i] = fmaxf(fmaxf(sv[0][i], sv[1][i]), fmaxf(sv[2][i], sv[3][i]));
        #pragma unroll
        for (int off = 1; off < 16; off <<= 1)
            #pragma unroll
            for (int i = 0; i < 4; ++i)
                rmax[i] = fmaxf(rmax[i], __shfl_xor(rmax[i], off));

        float fs[4];
        #pragma unroll
        for (int i = 0; i < 4; ++i) {
            float mn = fmaxf(m_i[i], rmax[i]);
            fs[i] = __expf(m_i[i] - mn);
            m_i[i] = mn;
        }

        float rsum[4] = {0.f, 0.f, 0.f, 0.f};
        #pragma unroll
        for (int ct = 0; ct < 4; ++ct)
            #pragma unroll
            for (int i = 0; i < 4; ++i) {
                float p = __expf(sv[ct][i] - m_i[i]);
                p_lds[w][kg * 4 + i][ct * 16 + lr] = (bf16_t)p;
                rsum[i] += p;
            }
        #pragma unroll
        for (int off = 1; off < 16; off <<= 1)
            #pragma unroll
            for (int i = 0; i < 4; ++i)
                rsum[i] += __shfl_xor(rsum[i], off);

        #pragma unroll
        for (int i = 0; i < 4; ++i)
            l_i[i] = l_i[i] * fs[i] + rsum[i];
        #pragma unroll
        for (int ct = 0; ct < 4; ++ct)
            #pragma unroll
            for (int i = 0; i < 4; ++i)
                o_acc[ct][i] *= fs[i];

        // O += P V, V^T frags straight from global
        bf16x8 pf[2];
        #pragma unroll
        for (int s = 0; s < 2; ++s)
            pf[s] = *(const bf16x8*)&p_lds[w][lr][s * 32 + kg * 8];
        __builtin_amdgcn_s_setprio(1);
        #pragma unroll
        for (int ct = 0; ct < 4; ++ct) {
            #pragma unroll
            for (int s = 0; s < 2; ++s) {
                bf16x8 vf = *(const bf16x8*)&vtb[((size_t)(b * 64 + ct * 16 + lr)) * T_ + kv0 + s * 32 + kg * 8];
                o_acc[ct] = __builtin_amdgcn_mfma_f32_16x16x32_bf16(pf[s], vf, o_acc[ct], 0, 0, 0);
            }
        }
        __builtin_amdgcn_s_setprio(0);
    }

    // publish per-wave partials (unnormalized O, m, l)
    #pragma unroll
    for (int ct = 0; ct < 4; ++ct)
        #pragma unroll
        for (int i = 0; i < 4; ++i)
            olds[w][kg * 4 + i][ct * 16 + lr] = o_acc[ct][i];
    if (lr == 0) {
        #pragma unroll
        for (int i = 0; i < 4; ++i) {
            mlds[w][kg * 4 + i] = m_i[i];
            llds[w][kg * 4 + i] = l_i[i];
        }
    }
    __syncthreads();

    // combine 4 wave-partials -> output
    for (int idx = tid; idx < 1024; idx += 256) {
        int r  = idx >> 6;
        int cc = idx & 63;
        float M = fmaxf(fmaxf(mlds[0][r], mlds[1][r]), fmaxf(mlds[2][r], mlds[3][r]));
        float lsum = 0.f, accv = 0.f;
        #pragma unroll
        for (int w4 = 0; w4 < 4; ++w4) {
            float e = __expf(mlds[w4][r] - M);
            lsum += e * llds[w4][r];
            accv += e * olds[w4][r][cc];
        }
        out[((size_t)(b * T_ + qrow0 + r)) * 64 + cc] = accv / lsum;
    }
}

extern "C" void kernel_launch(void* const* d_in, const int* in_sizes, int n_in,
                              void* d_out, int out_size, void* d_ws, size_t ws_size,
                              hipStream_t stream) {
    const float* x  = (const float*)d_in[0];
    const float* Wq = (const float*)d_in[1];
    const float* Wk = (const float*)d_in[2];
    const float* Wv = (const float*)d_in[3];
    float* out = (float*)d_out;

    bf16_t* ws  = (bf16_t*)d_ws;
    bf16_t* wbf = ws;                    // 3*64*1024       = 196608 elems
    bf16_t* qb  = ws + 196608;           // 16384*64        = 1048576
    bf16_t* kb  = qb + 1048576;
    bf16_t* vtb = kb + 1048576;          // [B][64][T]

    wcvt_kernel<<<768, 256, 0, stream>>>(Wq, Wk, Wv, wbf);
    qkv_proj_kernel<<<768, 256, 0, stream>>>(x, wbf, qb, kb, vtb);
    attn_kernel<<<1024, 256, 0, stream>>>(qb, kb, vtb, out);
}

// Round 3
// 152.621 us; speedup vs baseline: 1.0433x; 1.0213x over previous
//
#include <hip/hip_runtime.h>
#include <hip/hip_bf16.h>

#define B_ 4
#define T_ 4096
#define C_ 1024
#define H_ 64

typedef __bf16 bf16_t;
typedef __bf16 bf16x8 __attribute__((ext_vector_type(8)));
typedef float f32x4 __attribute__((ext_vector_type(4)));

// ---------------- Kernel A: convert W -> bf16 (Wq pre-scaled by 1/8, exact) --------
__global__ void wcvt_kernel(const float* __restrict__ Wq, const float* __restrict__ Wk,
                            const float* __restrict__ Wv, bf16_t* __restrict__ wbf) {
    int i = blockIdx.x * 256 + threadIdx.x;          // 0 .. 196607
    int m = i >> 16;
    int r = i & 65535;
    const float* src = (m == 0) ? Wq : (m == 1) ? Wk : Wv;
    float s = (m == 0) ? 0.125f : 1.0f;              // fold softmax scale into Wq
    wbf[i] = (bf16_t)(src[r] * s);
}

// ---------------- Kernel B: one-pass QKV projection ----------------
// grid = 1024 blocks (16 rows each), 256 threads (4 waves). Wave w owns 3 of the 12
// (matrix m, col-tile ct) pairs; all 4 waves share the same 16 x-rows (L1 hits).
// x read ONCE (64 MB); W streams from L2 (384 KB resident per XCD).
__global__ __launch_bounds__(256)
void qkv_proj_kernel(const float* __restrict__ x, const bf16_t* __restrict__ wbf,
                     bf16_t* __restrict__ qb, bf16_t* __restrict__ kb,
                     bf16_t* __restrict__ vtb) {
    int tid  = threadIdx.x;
    int w    = tid >> 6;
    int lane = tid & 63;
    int lr   = lane & 15;
    int kg   = lane >> 4;

    int row0 = blockIdx.x * 16;
    const float* xr = x + (size_t)(row0 + lr) * C_ + kg * 8;

    // pair p = w*3+j : m = p>>2, ct = p&3  (wave-uniform per j)
    const bf16_t* bp[3];
    int pm[3], pc[3];
    #pragma unroll
    for (int j = 0; j < 3; ++j) {
        int p = w * 3 + j;
        pm[j] = p >> 2;
        pc[j] = p & 3;
        bp[j] = wbf + (size_t)pm[j] * 65536 + (size_t)(pc[j] * 16 + lr) * 1024 + kg * 8;
    }

    f32x4 acc[3];
    #pragma unroll
    for (int j = 0; j < 3; ++j) acc[j] = (f32x4){0.f, 0.f, 0.f, 0.f};

    #pragma unroll 4
    for (int k0 = 0; k0 < C_; k0 += 32) {
        float4 a0 = *(const float4*)(xr + k0);
        float4 a1 = *(const float4*)(xr + k0 + 4);
        bf16x8 af;
        af[0] = (bf16_t)a0.x; af[1] = (bf16_t)a0.y; af[2] = (bf16_t)a0.z; af[3] = (bf16_t)a0.w;
        af[4] = (bf16_t)a1.x; af[5] = (bf16_t)a1.y; af[6] = (bf16_t)a1.z; af[7] = (bf16_t)a1.w;
        #pragma unroll
        for (int j = 0; j < 3; ++j) {
            bf16x8 bf = *(const bf16x8*)(bp[j] + k0);
            acc[j] = __builtin_amdgcn_mfma_f32_16x16x32_bf16(af, bf, acc[j], 0, 0, 0);
        }
    }

    #pragma unroll
    for (int j = 0; j < 3; ++j) {
        int m = pm[j];
        int h = pc[j] * 16 + lr;
        #pragma unroll
        for (int i = 0; i < 4; ++i) {
            int t = row0 + kg * 4 + i;
            if (m == 0) {
                qb[(size_t)t * 64 + h] = (bf16_t)acc[j][i];
            } else if (m == 1) {
                kb[(size_t)t * 64 + h] = (bf16_t)acc[j][i];
            } else {
                vtb[((size_t)(t >> 12) * 64 + h) * T_ + (t & 4095)] = (bf16_t)acc[j][i];
            }
        }
    }
}

// ---------------- Kernel C: causal flash attention, software-pipelined ----------------
// grid = 1024 blocks (16-row q-tile each, diag-heavy first), 256 threads = 4 waves
// splitting the KV range (strided 64-chunks). K prefetched one iteration ahead;
// V issued before softmax. No main-loop barriers. LDS combine at block end.
__global__ __launch_bounds__(256, 3)
void attn_kernel(const bf16_t* __restrict__ qb, const bf16_t* __restrict__ kb,
                 const bf16_t* __restrict__ vtb, float* __restrict__ out) {
    __shared__ float  olds[4][16][65];
    __shared__ float  mlds[4][16];
    __shared__ float  llds[4][16];
    __shared__ bf16_t p_lds[4][16][68];   // pitch 68: kg-row-groups on disjoint banks

    int tid  = threadIdx.x;
    int w    = tid >> 6;
    int lane = tid & 63;
    int lr   = lane & 15;
    int kg   = lane >> 4;

    int bid  = blockIdx.x;
    int b    = bid & 3;
    int t    = 255 - (bid >> 2);      // long tiles dispatched first
    int qrow0 = t * 16;

    bf16x8 qf[2];
    #pragma unroll
    for (int s = 0; s < 2; ++s)
        qf[s] = *(const bf16x8*)&qb[((size_t)(b * T_ + qrow0 + lr)) * 64 + s * 32 + kg * 8];

    f32x4 o_acc[4];
    float m_i[4], l_i[4];
    #pragma unroll
    for (int ct = 0; ct < 4; ++ct) o_acc[ct] = (f32x4){0.f, 0.f, 0.f, 0.f};
    #pragma unroll
    for (int i = 0; i < 4; ++i) { m_i[i] = -INFINITY; l_i[i] = 0.f; }

    int nchunks = (t >> 2) + 1;

    // prime the K pipeline
    bf16x8 kf[8];
    if (w < nchunks) {
        #pragma unroll
        for (int ct = 0; ct < 4; ++ct)
            #pragma unroll
            for (int s = 0; s < 2; ++s)
                kf[ct * 2 + s] = *(const bf16x8*)&kb[((size_t)(b * T_ + w * 64 + ct * 16 + lr)) * 64 + s * 32 + kg * 8];
    }

    for (int c = w; c < nchunks; c += 4) {
        int kv0 = c * 64;

        // S = Q K^T with pre-fetched K fragments
        f32x4 sc[4];
        #pragma unroll
        for (int ct = 0; ct < 4; ++ct) sc[ct] = (f32x4){0.f, 0.f, 0.f, 0.f};
        __builtin_amdgcn_s_setprio(1);
        #pragma unroll
        for (int ct = 0; ct < 4; ++ct)
            #pragma unroll
            for (int s = 0; s < 2; ++s)
                sc[ct] = __builtin_amdgcn_mfma_f32_16x16x32_bf16(qf[s], kf[ct * 2 + s], sc[ct], 0, 0, 0);
        __builtin_amdgcn_s_setprio(0);

        // issue V loads now (independent of softmax; latency hidden under it)
        bf16x8 vf[8];
        #pragma unroll
        for (int ct = 0; ct < 4; ++ct)
            #pragma unroll
            for (int s = 0; s < 2; ++s)
                vf[ct * 2 + s] = *(const bf16x8*)&vtb[((size_t)(b * 64 + ct * 16 + lr)) * T_ + kv0 + s * 32 + kg * 8];

        // prefetch next K chunk (clamped address on last iteration; result unused)
        int cn = c + 4;
        int cl = (cn < nchunks) ? cn : c;
        bf16x8 kn[8];
        #pragma unroll
        for (int ct = 0; ct < 4; ++ct)
            #pragma unroll
            for (int s = 0; s < 2; ++s)
                kn[ct * 2 + s] = *(const bf16x8*)&kb[((size_t)(b * T_ + cl * 64 + ct * 16 + lr)) * 64 + s * 32 + kg * 8];

        // mask + online softmax
        bool needMask = (kv0 + 63 > qrow0);
        float sv[4][4];
        #pragma unroll
        for (int ct = 0; ct < 4; ++ct)
            #pragma unroll
            for (int i = 0; i < 4; ++i) {
                float v = sc[ct][i];
                if (needMask) {
                    int col = kv0 + ct * 16 + lr;
                    int rw  = qrow0 + kg * 4 + i;
                    if (col > rw) v = -INFINITY;
                }
                sv[ct][i] = v;
            }

        float rmax[4];
        #pragma unroll
        for (int i = 0; i < 4; ++i)
            rmax[i] = fmaxf(fmaxf(sv[0][i], sv[1][i]), fmaxf(sv[2][i], sv[3][i]));
        #pragma unroll
        for (int off = 1; off < 16; off <<= 1)
            #pragma unroll
            for (int i = 0; i < 4; ++i)
                rmax[i] = fmaxf(rmax[i], __shfl_xor(rmax[i], off));

        float fs[4];
        #pragma unroll
        for (int i = 0; i < 4; ++i) {
            float mn = fmaxf(m_i[i], rmax[i]);
            fs[i] = __expf(m_i[i] - mn);
            m_i[i] = mn;
        }

        float rsum[4] = {0.f, 0.f, 0.f, 0.f};
        #pragma unroll
        for (int ct = 0; ct < 4; ++ct)
            #pragma unroll
            for (int i = 0; i < 4; ++i) {
                float p = __expf(sv[ct][i] - m_i[i]);
                p_lds[w][kg * 4 + i][ct * 16 + lr] = (bf16_t)p;
                rsum[i] += p;
            }
        #pragma unroll
        for (int off = 1; off < 16; off <<= 1)
            #pragma unroll
            for (int i = 0; i < 4; ++i)
                rsum[i] += __shfl_xor(rsum[i], off);

        #pragma unroll
        for (int i = 0; i < 4; ++i)
            l_i[i] = l_i[i] * fs[i] + rsum[i];
        #pragma unroll
        for (int ct = 0; ct < 4; ++ct)
            #pragma unroll
            for (int i = 0; i < 4; ++i)
                o_acc[ct][i] *= fs[i];

        // O += P V
        bf16x8 pf[2];
        #pragma unroll
        for (int s = 0; s < 2; ++s)
            pf[s] = *(const bf16x8*)&p_lds[w][lr][s * 32 + kg * 8];
        __builtin_amdgcn_s_setprio(1);
        #pragma unroll
        for (int ct = 0; ct < 4; ++ct)
            #pragma unroll
            for (int s = 0; s < 2; ++s)
                o_acc[ct] = __builtin_amdgcn_mfma_f32_16x16x32_bf16(pf[s], vf[ct * 2 + s], o_acc[ct], 0, 0, 0);
        __builtin_amdgcn_s_setprio(0);

        // rotate K pipeline
        #pragma unroll
        for (int j = 0; j < 8; ++j) kf[j] = kn[j];
    }

    // publish per-wave partials (unnormalized O, m, l)
    #pragma unroll
    for (int ct = 0; ct < 4; ++ct)
        #pragma unroll
        for (int i = 0; i < 4; ++i)
            olds[w][kg * 4 + i][ct * 16 + lr] = o_acc[ct][i];
    if (lr == 0) {
        #pragma unroll
        for (int i = 0; i < 4; ++i) {
            mlds[w][kg * 4 + i] = m_i[i];
            llds[w][kg * 4 + i] = l_i[i];
        }
    }
    __syncthreads();

    // combine 4 wave-partials -> output
    for (int idx = tid; idx < 1024; idx += 256) {
        int r  = idx >> 6;
        int cc = idx & 63;
        float M = fmaxf(fmaxf(mlds[0][r], mlds[1][r]), fmaxf(mlds[2][r], mlds[3][r]));
        float lsum = 0.f, accv = 0.f;
        #pragma unroll
        for (int w4 = 0; w4 < 4; ++w4) {
            float e = __expf(mlds[w4][r] - M);
            lsum += e * llds[w4][r];
            accv += e * olds[w4][r][cc];
        }
        out[((size_t)(b * T_ + qrow0 + r)) * 64 + cc] = accv / lsum;
    }
}

extern "C" void kernel_launch(void* const* d_in, const int* in_sizes, int n_in,
                              void* d_out, int out_size, void* d_ws, size_t ws_size,
                              hipStream_t stream) {
    const float* x  = (const float*)d_in[0];
    const float* Wq = (const float*)d_in[1];
    const float* Wk = (const float*)d_in[2];
    const float* Wv = (const float*)d_in[3];
    float* out = (float*)d_out;

    bf16_t* ws  = (bf16_t*)d_ws;
    bf16_t* wbf = ws;                    // 3*64*1024       = 196608 elems
    bf16_t* qb  = ws + 196608;           // 16384*64        = 1048576
    bf16_t* kb  = qb + 1048576;
    bf16_t* vtb = kb + 1048576;          // [B][64][T]

    wcvt_kernel<<<768, 256, 0, stream>>>(Wq, Wk, Wv, wbf);
    qkv_proj_kernel<<<1024, 256, 0, stream>>>(x, wbf, qb, kb, vtb);
    attn_kernel<<<1024, 256, 0, stream>>>(qb, kb, vtb, out);
}